// Round 9
// baseline (349.868 us; speedup 1.0000x reference)
//
#include <hip/hip_runtime.h>
#include <stdint.h>

// Problem constants (reference: N=10000, F_IN=256, HID=256, OUT=512, H=4, E=320000)
#define N_NODES 10000
#define K_DIM   256
#define HID_D   256
#define OUT_D   512
#define NE      320000
#define NE_TOT  (NE + N_NODES)   // + self loops
#define SLOPE   0.2f
#define LN_EPS  1e-5f
#define NPH     5                 // source buckets of 2048 (10000 >> 11 = 4 max)
#define NBUCK   (N_NODES * NPH)

typedef __bf16 bf16x8 __attribute__((ext_vector_type(8)));
typedef float  f32x4  __attribute__((ext_vector_type(4)));
typedef float  f32x2  __attribute__((ext_vector_type(2)));
typedef unsigned short u16;
typedef uint32_t u32;

#if __has_builtin(__builtin_elementwise_fma)
#define PKFMA(a,b,c) __builtin_elementwise_fma((a),(b),(c))
#else
#define PKFMA(a,b,c) ((a)*(b)+(c))
#endif
#if __has_builtin(__builtin_elementwise_max)
#define PKMAX(a,b) __builtin_elementwise_max((a),(b))
#else
static __device__ __forceinline__ f32x2 pkmax_(f32x2 a, f32x2 b) {
    f32x2 r; r.x = fmaxf(a.x, b.x); r.y = fmaxf(a.y, b.y); return r;
}
#define PKMAX(a,b) pkmax_((a),(b))
#endif

__device__ __forceinline__ float bf2f(u16 u) {
    union { u32 i; float f; } v; v.i = ((u32)u) << 16; return v.f;
}
__device__ __forceinline__ u16 f2bf(float f) {
    union { float f; u32 i; } v; v.f = f;
    u32 b = v.i;
    return (u16)((b + 0x7FFFu + ((b >> 16) & 1u)) >> 16);
}
// one dword = 2 packed bf16 -> float2 {lo, hi}
__device__ __forceinline__ f32x2 bfpair(u32 u) {
    union { u32 i; float f; } lo, hi;
    lo.i = u << 16; hi.i = u & 0xFFFF0000u;
    f32x2 r; r.x = lo.f; r.y = hi.f; return r;
}
__device__ __forceinline__ u32 pack2bf(float a, float b) {
    return (u32)f2bf(a) | ((u32)f2bf(b) << 16);
}

// async global->LDS, 16B per lane; LDS dest is wave-uniform base + lane*16 (m104)
__device__ __forceinline__ void gl_lds16(const u16* g, u16* lds_base) {
    __builtin_amdgcn_global_load_lds(
        (const __attribute__((address_space(1))) void*)g,
        (__attribute__((address_space(3))) void*)lds_base, 16, 0, 0);
}

// ---------------- fused prep: dtype-vote + (conditional) canon + bucket-count ----
// canon segments: x(2,560,000) wl1(65,536) wr1(65,536) wl2(131,072) wr2(131,072)
#define CW_X  2560000
#define CW_1  (CW_X + 65536)
#define CW_2  (CW_1 + 65536)
#define CW_3  (CW_2 + 131072)
#define CW_TOT (CW_3 + 131072)            // 2,953,216 = 256 * 11536
#define CANON_BLOCKS (CW_TOT / 256 + 16)  // + 16 blocks for small vectors (4096)
#define COUNT_BLOCKS ((NE + 255) / 256)

struct PrepArgs {
    const void *x, *wl1, *wr1, *wl2, *wr2;
    u16 *xd, *wl1d, *wr1d, *wl2d, *wr2d;
    const void* ssrc[10]; float* sdst[10];
    const int* ei; int* bcnt; int* flagg;
};

__global__ __launch_bounds__(256) void k_prep(PrepArgs c) {
    int bx = blockIdx.x, tid = threadIdx.x;
    if (bx >= CANON_BLOCKS) {           // bucket-count section
        int e = (bx - CANON_BLOCKS) * 256 + tid;
        if (e < NE) {
            int s = c.ei[e], d = c.ei[NE + e];
            atomicAdd(&c.bcnt[d * NPH + (s >> 11)], 1);
        }
        return;
    }
    // local dtype vote (same 256 dwords of x in every block -> deterministic):
    // bf16-packed -> low 16 bits are a bf16 of N(0,1) data, exp field in ~[112,133]
    __shared__ int cnt;
    if (tid == 0) cnt = 0;
    __syncthreads();
    u32 v = ((const u32*)c.x)[tid];
    int e_lo = (int)((v >> 7) & 0xFF);
    if (e_lo >= 100 && e_lo <= 150) atomicAdd(&cnt, 1);
    __syncthreads();
    int f = (cnt > 180) ? 1 : 0;        // 1 = bf16-packed inputs
    if (bx == 0 && tid == 0) *c.flagg = f;

    int i = bx * 256 + tid;
    if (i < CW_TOT) {
        if (f) return;                  // bf16 inputs: GEMM reads d_in directly
        const void* src; u16* dst; int off;
        if      (i < CW_X) { src = c.x;   dst = c.xd;   off = i; }
        else if (i < CW_1) { src = c.wl1; dst = c.wl1d; off = i - CW_X; }
        else if (i < CW_2) { src = c.wr1; dst = c.wr1d; off = i - CW_1; }
        else if (i < CW_3) { src = c.wl2; dst = c.wl2d; off = i - CW_2; }
        else               { src = c.wr2; dst = c.wr2d; off = i - CW_3; }
        dst[off] = f2bf(((const float*)src)[off]);
    } else {
        // small vectors (always run): 4 segs of 256 then 6 segs of 512
        int s = i - CW_TOT;
        int seg, off;
        if (s < 1024) { seg = s >> 8; off = s & 255; }
        else          { seg = 4 + ((s - 1024) >> 9); off = (s - 1024) & 511; }
        const void* sp = c.ssrc[seg];
        float* d = c.sdst[seg];
        d[off] = f ? bf2f(((const u16*)sp)[off]) : ((const float*)sp)[off];
    }
}

// ---------------- bucket scan (self-loop folded into bucket (i, i>>11)) ----------
// flat domain b in [0, NBUCK]; node i = b/NPH, phase = b%NPH.
// rowptr[i] = prefix at b = i*NPH; cursor[b] for the ordered scatter.
__global__ __launch_bounds__(1024) void k_scan(const int* __restrict__ bcnt,
                                               int* __restrict__ rowptr,
                                               int* __restrict__ cursor) {
    __shared__ int sbuf[2][1024];
    const int Q = 49;                 // 1024*49 = 50176 >= NBUCK+1
    int t = threadIdx.x;
    int base = t * Q;
    auto bval = [&](int b) -> int {
        if (b >= NBUCK) return 0;
        int i = b / NPH, ph = b - i * NPH;
        return bcnt[b] + ((i >> 11) == ph ? 1 : 0);   // +1 self-loop
    };
    int s = 0;
    for (int q = 0; q < Q; ++q) s += bval(base + q);
    sbuf[0][t] = s;
    __syncthreads();
    int cur = 0;
    for (int off = 1; off < 1024; off <<= 1) {
        int nxt = cur ^ 1;
        int v = sbuf[cur][t];
        if (t >= off) v += sbuf[cur][t - off];
        sbuf[nxt][t] = v;
        __syncthreads();
        cur = nxt;
    }
    int run = sbuf[cur][t] - s;       // exclusive prefix of this thread's chunk
    for (int q = 0; q < Q; ++q) {
        int b = base + q;
        if (b <= NBUCK) {
            if (b < NBUCK) cursor[b] = run;
            int i = b / NPH, ph = b - i * NPH;
            if (ph == 0) rowptr[i] = run;   // covers rowptr[N_NODES] at b==NBUCK
            run += bval(b);
        }
    }
}

// ---------------- LDS-tiled GEMM pair (+ bucket-ordered scatter tail blocks) -----
// X/W pointers selected by *flag (raw bf16 inputs vs fp32-canon scratch).
__global__ __launch_bounds__(256) void k_gemm2s(const u16* __restrict__ Xa,   // raw
                                                const u16* __restrict__ Xb,   // canon
                                                const u16* __restrict__ Wla,
                                                const u16* __restrict__ Wlb,
                                                const u16* __restrict__ Wra,
                                                const u16* __restrict__ Wrb,
                                                const float* __restrict__ bl,
                                                const float* __restrict__ br,
                                                u16* __restrict__ Yl,
                                                u16* __restrict__ Yr, int Ncols,
                                                int MBx, int gemmB,
                                                const int* __restrict__ ei,
                                                int* cursor, int* __restrict__ csr_src,
                                                const int* __restrict__ flag) {
    __shared__ uint4 sAq[1024];   // 16 KB: A tile, slot = chunk*128 + m (chunk=k/8)
    __shared__ uint4 sBq[1024];   // 16 KB: B tile, slot = chunk*128 + n
    int bx = blockIdx.x, tid = threadIdx.x;

    if (bx >= gemmB) {            // ordered scatter section
        int e = (bx - gemmB) * 256 + tid;
        if (e < NE_TOT) {
            int s, d;
            if (e < NE) { s = ei[e]; d = ei[NE + e]; }
            else        { s = e - NE; d = s; }
            int pos = atomicAdd(&cursor[d * NPH + (s >> 11)], 1);
            csr_src[pos] = s;
        }
        return;
    }

    int f = *flag;
    const u16* X  = f ? Xa  : Xb;
    const u16* Wl = f ? Wla : Wlb;
    const u16* Wr = f ? Wra : Wrb;

    u16* sA = (u16*)sAq;
    u16* sB = (u16*)sBq;
    int nb = Ncols >> 7;
    int by = bx / MBx;
    const u16* W; const float* bias; u16* Y; int nbase;
    if (by < nb) { W = Wl; bias = bl; Y = Yl; nbase = by << 7; }
    else         { W = Wr; bias = br; Y = Yr; nbase = (by - nb) << 7; }

    int m0   = (bx % MBx) << 7;
    int wave = tid >> 6;
    int lane = tid & 63;
    int quad = lane >> 4;
    int l16  = lane & 15;
    int wm   = wave & 1;
    int wn   = wave >> 1;

    f32x4 acc[4][4] = {};

    #pragma unroll 1
    for (int kk = 0; kk < K_DIM; kk += 64) {
        #pragma unroll
        for (int r = 0; r < 4; ++r) {
            int g = wave + r * 4;
            int chunk = g >> 1;
            int row = ((g & 1) << 6) + lane;
            int mg = m0 + row;
            if (mg >= N_NODES) mg = N_NODES - 1;   // clamp: dup data, stores guarded
            gl_lds16(X + (size_t)mg * K_DIM + kk + chunk * 8, sA + (size_t)(g << 6) * 8);
            gl_lds16(W + (size_t)(nbase + row) * K_DIM + kk + chunk * 8, sB + (size_t)(g << 6) * 8);
        }
        __syncthreads();

        #pragma unroll
        for (int s = 0; s < 2; ++s) {
            int c = s * 4 + quad;
            bf16x8 af[4], bf[4];
            #pragma unroll
            for (int t = 0; t < 4; ++t) {
                int m = (wm << 6) + t * 16 + l16;
                af[t] = *(const bf16x8*)(sA + ((size_t)(c << 7) + m) * 8);
                int n = (wn << 6) + t * 16 + l16;
                bf[t] = *(const bf16x8*)(sB + ((size_t)(c << 7) + n) * 8);
            }
            #pragma unroll
            for (int mt = 0; mt < 4; ++mt)
                #pragma unroll
                for (int nt = 0; nt < 4; ++nt)
                    acc[mt][nt] = __builtin_amdgcn_mfma_f32_16x16x32_bf16(
                        af[mt], bf[nt], acc[mt][nt], 0, 0, 0);
        }
        __syncthreads();
    }

    #pragma unroll
    for (int nt = 0; nt < 4; ++nt) {
        int col = nbase + (wn << 6) + nt * 16 + l16;
        float bv = bias[col];
        #pragma unroll
        for (int mt = 0; mt < 4; ++mt) {
            int rbase = m0 + (wm << 6) + mt * 16 + quad * 4;
            #pragma unroll
            for (int q = 0; q < 4; ++q) {
                int row = rbase + q;
                if (row < N_NODES)
                    Y[(size_t)row * Ncols + col] = f2bf(acc[mt][nt][q] + bv);
            }
        }
    }
}

// ---------------- Layer-1 fused attention + aggregation (+bias+ReLU) ----------------
// 1 wave/node (4 nodes/block); lane owns 4 ch: c0 = head*64+(lane&15)*4.
// Edge lists are source-bucket sorted -> concurrent waves sweep the xl table.
__global__ __launch_bounds__(256) void k_agg1(const u16* __restrict__ xl,
                                              const u16* __restrict__ xr,
                                              const int* __restrict__ rowptr,
                                              const int* __restrict__ csrc,
                                              const float* __restrict__ att,
                                              const float* __restrict__ bias,
                                              u16* __restrict__ hout) {
    int wave = threadIdx.x >> 6, lane = threadIdx.x & 63;
    int i = blockIdx.x * 4 + wave;
    if (i >= N_NODES) return;
    int c0 = (lane >> 4) * 64 + (lane & 15) * 4;

    f32x2 xp[2], ap[2];
    {
        uint2 xq = *(const uint2*)(xr + (size_t)i * HID_D + c0);
        xp[0] = bfpair(xq.x); xp[1] = bfpair(xq.y);
        const f32x2* a2 = (const f32x2*)(att + c0);
        ap[0] = a2[0]; ap[1] = a2[1];
    }
    const f32x2 slope2 = {SLOPE, SLOPE};

    int p = rowptr[i], pend = rowptr[i + 1];
    float denom = 0.f;
    f32x2 acc[2] = {};
    const u16* xbase = xl + c0;

    auto dotq = [&](uint2 q) -> float {
        f32x2 pr2 = {0.f, 0.f};
        f32x2 s = bfpair(q.x) + xp[0]; s = PKMAX(s, s * slope2); pr2 = PKFMA(s, ap[0], pr2);
        s = bfpair(q.y) + xp[1];       s = PKMAX(s, s * slope2); pr2 = PKFMA(s, ap[1], pr2);
        return pr2.x + pr2.y;
    };
    auto accq = [&](uint2 q, float w) {
        f32x2 W = {w, w};
        acc[0] = PKFMA(W, bfpair(q.x), acc[0]);
        acc[1] = PKFMA(W, bfpair(q.y), acc[1]);
    };

    while (p + 8 <= pend) {
        int4 ja = *(const int4*)(csrc + p);
        int4 jb = *(const int4*)(csrc + p + 4);
        uint2 q[8];
        q[0] = *(const uint2*)(xbase + (size_t)ja.x * HID_D);
        q[1] = *(const uint2*)(xbase + (size_t)ja.y * HID_D);
        q[2] = *(const uint2*)(xbase + (size_t)ja.z * HID_D);
        q[3] = *(const uint2*)(xbase + (size_t)ja.w * HID_D);
        q[4] = *(const uint2*)(xbase + (size_t)jb.x * HID_D);
        q[5] = *(const uint2*)(xbase + (size_t)jb.y * HID_D);
        q[6] = *(const uint2*)(xbase + (size_t)jb.z * HID_D);
        q[7] = *(const uint2*)(xbase + (size_t)jb.w * HID_D);
        float pr[8];
        #pragma unroll
        for (int e = 0; e < 8; ++e) pr[e] = dotq(q[e]);
        #pragma unroll
        for (int o = 1; o < 16; o <<= 1)
            #pragma unroll
            for (int e = 0; e < 8; ++e) pr[e] += __shfl_xor(pr[e], o, 64);
        #pragma unroll
        for (int e = 0; e < 8; ++e) {
            float w = __expf(fminf(pr[e], 60.f));
            denom += w;
            accq(q[e], w);
        }
        p += 8;
    }
    if (p + 4 <= pend) {
        int4 ja = *(const int4*)(csrc + p);
        uint2 q[4];
        q[0] = *(const uint2*)(xbase + (size_t)ja.x * HID_D);
        q[1] = *(const uint2*)(xbase + (size_t)ja.y * HID_D);
        q[2] = *(const uint2*)(xbase + (size_t)ja.z * HID_D);
        q[3] = *(const uint2*)(xbase + (size_t)ja.w * HID_D);
        float pr[4];
        #pragma unroll
        for (int e = 0; e < 4; ++e) pr[e] = dotq(q[e]);
        #pragma unroll
        for (int o = 1; o < 16; o <<= 1)
            #pragma unroll
            for (int e = 0; e < 4; ++e) pr[e] += __shfl_xor(pr[e], o, 64);
        #pragma unroll
        for (int e = 0; e < 4; ++e) {
            float w = __expf(fminf(pr[e], 60.f));
            denom += w;
            accq(q[e], w);
        }
        p += 4;
    }
    for (; p < pend; ++p) {
        uint2 q = *(const uint2*)(xbase + (size_t)csrc[p] * HID_D);
        float pr = dotq(q);
        #pragma unroll
        for (int o = 1; o < 16; o <<= 1) pr += __shfl_xor(pr, o, 64);
        float w = __expf(fminf(pr, 60.f));
        denom += w;
        accq(q, w);
    }

    float inv = 1.f / denom;
    f32x2 inv2 = {inv, inv};
    const f32x2* bp = (const f32x2*)(bias + c0);
    f32x2 z = {0.f, 0.f};
    f32x2 o0 = PKMAX(PKFMA(acc[0], inv2, bp[0]), z);   // + bias, ReLU
    f32x2 o1 = PKMAX(PKFMA(acc[1], inv2, bp[1]), z);
    u32* hp = (u32*)(hout + (size_t)i * HID_D + c0);
    hp[0] = pack2bf(o0.x, o0.y);
    hp[1] = pack2bf(o1.x, o1.y);
}

// ---------------- Layer-2 fused attention + aggregation + LayerNorm ----------------
// 1 wave/node; lane owns 8 ch: c0 = head*128+(lane&15)*8. Bucket-sorted lists.
__global__ __launch_bounds__(256) void k_agg2_ln(const u16* __restrict__ xl,
                                                 const u16* __restrict__ xr,
                                                 const int* __restrict__ rowptr,
                                                 const int* __restrict__ csrc,
                                                 const float* __restrict__ att,
                                                 const float* __restrict__ bias,
                                                 const float* __restrict__ gamma,
                                                 const float* __restrict__ beta,
                                                 void* __restrict__ outv,
                                                 const int* __restrict__ flag) {
    int wave = threadIdx.x >> 6, lane = threadIdx.x & 63;
    int i = blockIdx.x * 4 + wave;
    if (i >= N_NODES) return;
    int c0 = (lane >> 4) * 128 + (lane & 15) * 8;

    f32x2 xp[4], ap[4];
    {
        uint4 xq = *(const uint4*)(xr + (size_t)i * OUT_D + c0);
        xp[0] = bfpair(xq.x); xp[1] = bfpair(xq.y);
        xp[2] = bfpair(xq.z); xp[3] = bfpair(xq.w);
        const f32x2* a2 = (const f32x2*)(att + c0);
        ap[0] = a2[0]; ap[1] = a2[1]; ap[2] = a2[2]; ap[3] = a2[3];
    }
    const f32x2 slope2 = {SLOPE, SLOPE};

    int p = rowptr[i], pend = rowptr[i + 1];
    float denom = 0.f;
    f32x2 acc[4] = {};
    const u16* xbase = xl + c0;

    auto dotq = [&](uint4 q) -> float {
        f32x2 pr2 = {0.f, 0.f};
        f32x2 s = bfpair(q.x) + xp[0]; s = PKMAX(s, s * slope2); pr2 = PKFMA(s, ap[0], pr2);
        s = bfpair(q.y) + xp[1];       s = PKMAX(s, s * slope2); pr2 = PKFMA(s, ap[1], pr2);
        s = bfpair(q.z) + xp[2];       s = PKMAX(s, s * slope2); pr2 = PKFMA(s, ap[2], pr2);
        s = bfpair(q.w) + xp[3];       s = PKMAX(s, s * slope2); pr2 = PKFMA(s, ap[3], pr2);
        return pr2.x + pr2.y;
    };
    auto accq = [&](uint4 q, float w) {
        f32x2 W = {w, w};
        acc[0] = PKFMA(W, bfpair(q.x), acc[0]);
        acc[1] = PKFMA(W, bfpair(q.y), acc[1]);
        acc[2] = PKFMA(W, bfpair(q.z), acc[2]);
        acc[3] = PKFMA(W, bfpair(q.w), acc[3]);
    };

    while (p + 8 <= pend) {
        int4 ja = *(const int4*)(csrc + p);
        int4 jb = *(const int4*)(csrc + p + 4);
        uint4 q[8];
        q[0] = *(const uint4*)(xbase + (size_t)ja.x * OUT_D);
        q[1] = *(const uint4*)(xbase + (size_t)ja.y * OUT_D);
        q[2] = *(const uint4*)(xbase + (size_t)ja.z * OUT_D);
        q[3] = *(const uint4*)(xbase + (size_t)ja.w * OUT_D);
        q[4] = *(const uint4*)(xbase + (size_t)jb.x * OUT_D);
        q[5] = *(const uint4*)(xbase + (size_t)jb.y * OUT_D);
        q[6] = *(const uint4*)(xbase + (size_t)jb.z * OUT_D);
        q[7] = *(const uint4*)(xbase + (size_t)jb.w * OUT_D);
        float pr[8];
        #pragma unroll
        for (int e = 0; e < 8; ++e) pr[e] = dotq(q[e]);
        #pragma unroll
        for (int o = 1; o < 16; o <<= 1)
            #pragma unroll
            for (int e = 0; e < 8; ++e) pr[e] += __shfl_xor(pr[e], o, 64);
        #pragma unroll
        for (int e = 0; e < 8; ++e) {
            float w = __expf(fminf(pr[e], 60.f));
            denom += w;
            accq(q[e], w);
        }
        p += 8;
    }
    if (p + 4 <= pend) {
        int4 ja = *(const int4*)(csrc + p);
        uint4 q[4];
        q[0] = *(const uint4*)(xbase + (size_t)ja.x * OUT_D);
        q[1] = *(const uint4*)(xbase + (size_t)ja.y * OUT_D);
        q[2] = *(const uint4*)(xbase + (size_t)ja.z * OUT_D);
        q[3] = *(const uint4*)(xbase + (size_t)ja.w * OUT_D);
        float pr[4];
        #pragma unroll
        for (int e = 0; e < 4; ++e) pr[e] = dotq(q[e]);
        #pragma unroll
        for (int o = 1; o < 16; o <<= 1)
            #pragma unroll
            for (int e = 0; e < 4; ++e) pr[e] += __shfl_xor(pr[e], o, 64);
        #pragma unroll
        for (int e = 0; e < 4; ++e) {
            float w = __expf(fminf(pr[e], 60.f));
            denom += w;
            accq(q[e], w);
        }
        p += 4;
    }
    for (; p < pend; ++p) {
        uint4 q = *(const uint4*)(xbase + (size_t)csrc[p] * OUT_D);
        float pr = dotq(q);
        #pragma unroll
        for (int o = 1; o < 16; o <<= 1) pr += __shfl_xor(pr, o, 64);
        float w = __expf(fminf(pr, 60.f));
        denom += w;
        accq(q, w);
    }

    float inv = 1.f / denom;
    f32x2 inv2 = {inv, inv};
    const f32x2* bp = (const f32x2*)(bias + c0);
    f32x2 o2[4];
    float s1 = 0.f, s2 = 0.f;
    #pragma unroll
    for (int k = 0; k < 4; ++k) {
        o2[k] = PKFMA(acc[k], inv2, bp[k]);
        s1 += o2[k].x + o2[k].y;
        s2 = fmaf(o2[k].x, o2[k].x, fmaf(o2[k].y, o2[k].y, s2));
    }
    #pragma unroll
    for (int off = 1; off < 64; off <<= 1) {
        s1 += __shfl_xor(s1, off, 64);
        s2 += __shfl_xor(s2, off, 64);
    }
    float mu  = s1 * (1.f / OUT_D);
    float var = s2 * (1.f / OUT_D) - mu * mu;
    float rstd = rsqrtf(var + LN_EPS);
    f32x2 mu2 = {mu, mu}, rs2 = {rstd, rstd};
    const f32x2* gp  = (const f32x2*)(gamma + c0);
    const f32x2* bep = (const f32x2*)(beta + c0);

    size_t ob = (size_t)i * OUT_D + c0;
    if (*flag) {
        u32 pk[4];
        #pragma unroll
        for (int k = 0; k < 4; ++k) {
            f32x2 r = PKFMA(gp[k] * (o2[k] - mu2), rs2, bep[k]);
            pk[k] = pack2bf(r.x, r.y);
        }
        *(uint4*)((u16*)outv + ob) = make_uint4(pk[0], pk[1], pk[2], pk[3]);
    } else {
        f32x2* out = (f32x2*)((float*)outv + ob);
        #pragma unroll
        for (int k = 0; k < 4; ++k)
            out[k] = PKFMA(gp[k] * (o2[k] - mu2), rs2, bep[k]);
    }
}

// ---------------- launcher ----------------

extern "C" void kernel_launch(void* const* d_in, const int* in_sizes, int n_in,
                              void* d_out, int out_size, void* d_ws, size_t ws_size,
                              hipStream_t stream) {
    const int* ei = (const int*)d_in[1];

    char* ws = (char*)d_ws;
    size_t off = 0;
    auto alloc = [&](size_t bytes) { void* p = ws + off; off += (bytes + 255) & ~(size_t)255; return p; };
    u16* xcb  = (u16*)alloc((size_t)N_NODES * K_DIM * 2);
    u16* wl1b = (u16*)alloc((size_t)HID_D * K_DIM * 2);
    u16* wr1b = (u16*)alloc((size_t)HID_D * K_DIM * 2);
    u16* wl2b = (u16*)alloc((size_t)OUT_D * K_DIM * 2);
    u16* wr2b = (u16*)alloc((size_t)OUT_D * K_DIM * 2);
    u16* xl1b = (u16*)alloc((size_t)N_NODES * HID_D * 2);
    u16* xr1b = (u16*)alloc((size_t)N_NODES * HID_D * 2);
    u16* hb   = (u16*)alloc((size_t)N_NODES * HID_D * 2);
    u16* xl2b = (u16*)alloc((size_t)N_NODES * OUT_D * 2);
    u16* xr2b = (u16*)alloc((size_t)N_NODES * OUT_D * 2);
    float* bl1c  = (float*)alloc(HID_D * 4);
    float* br1c  = (float*)alloc(HID_D * 4);
    float* att1c = (float*)alloc(HID_D * 4);
    float* bia1c = (float*)alloc(HID_D * 4);
    float* bl2c  = (float*)alloc(OUT_D * 4);
    float* br2c  = (float*)alloc(OUT_D * 4);
    float* att2c = (float*)alloc(OUT_D * 4);
    float* bia2c = (float*)alloc(OUT_D * 4);
    float* gamc  = (float*)alloc(OUT_D * 4);
    float* betc  = (float*)alloc(OUT_D * 4);
    int* flag = (int*)alloc(256);
    int* bcnt = (int*)alloc((size_t)NBUCK * 4);
    int* rowp = (int*)alloc((size_t)(N_NODES + 1) * 4);
    int* curs = (int*)alloc((size_t)NBUCK * 4);
    int* csrc = (int*)alloc((size_t)NE_TOT * 4);

    hipMemsetAsync(bcnt, 0, (size_t)NBUCK * 4, stream);

    PrepArgs pa;
    pa.x = d_in[0]; pa.wl1 = d_in[2]; pa.wr1 = d_in[4]; pa.wl2 = d_in[8]; pa.wr2 = d_in[10];
    pa.xd = xcb; pa.wl1d = wl1b; pa.wr1d = wr1b; pa.wl2d = wl2b; pa.wr2d = wr2b;
    pa.ssrc[0] = d_in[3];  pa.sdst[0] = bl1c;
    pa.ssrc[1] = d_in[5];  pa.sdst[1] = br1c;
    pa.ssrc[2] = d_in[6];  pa.sdst[2] = att1c;
    pa.ssrc[3] = d_in[7];  pa.sdst[3] = bia1c;
    pa.ssrc[4] = d_in[9];  pa.sdst[4] = bl2c;
    pa.ssrc[5] = d_in[11]; pa.sdst[5] = br2c;
    pa.ssrc[6] = d_in[12]; pa.sdst[6] = att2c;
    pa.ssrc[7] = d_in[13]; pa.sdst[7] = bia2c;
    pa.ssrc[8] = d_in[14]; pa.sdst[8] = gamc;
    pa.ssrc[9] = d_in[15]; pa.sdst[9] = betc;
    pa.ei = ei; pa.bcnt = bcnt; pa.flagg = flag;
    hipLaunchKernelGGL(k_prep, dim3(CANON_BLOCKS + COUNT_BLOCKS), dim3(256), 0, stream, pa);

    hipLaunchKernelGGL(k_scan, dim3(1), dim3(1024), 0, stream, bcnt, rowp, curs);

    const int MB = (N_NODES + 127) / 128;     // 79
    const int SCATB = (NE_TOT + 255) / 256;   // 1290
    // layer-1 GEMM pair + ordered-scatter tail blocks
    hipLaunchKernelGGL(k_gemm2s, dim3(MB * 4 + SCATB), dim3(256), 0, stream,
                       (const u16*)d_in[0], xcb,
                       (const u16*)d_in[2], wl1b,
                       (const u16*)d_in[4], wr1b,
                       bl1c, br1c, xl1b, xr1b, HID_D,
                       MB, MB * 4, ei, curs, csrc, flag);
    hipLaunchKernelGGL(k_agg1, dim3((N_NODES + 3) / 4), dim3(256), 0, stream,
                       xl1b, xr1b, rowp, csrc, att1c, bia1c, hb);
    // layer-2 GEMM pair (X = hb from scratch; raw==canon)
    hipLaunchKernelGGL(k_gemm2s, dim3(MB * 8), dim3(256), 0, stream,
                       hb, hb,
                       (const u16*)d_in[8], wl2b,
                       (const u16*)d_in[10], wr2b,
                       bl2c, br2c, xl2b, xr2b, OUT_D,
                       MB, MB * 8, ei, curs, csrc, flag);
    hipLaunchKernelGGL(k_agg2_ln, dim3((N_NODES + 3) / 4), dim3(256), 0, stream,
                       xl2b, xr2b, rowp, csrc, att2c, bia2c, gamc, betc, d_out, flag);
}

// Round 10
// 259.143 us; speedup vs baseline: 1.3501x; 1.3501x over previous
//
#include <hip/hip_runtime.h>
#include <stdint.h>

// Problem constants (reference: N=10000, F_IN=256, HID=256, OUT=512, H=4, E=320000)
#define N_NODES 10000
#define K_DIM   256
#define HID_D   256
#define OUT_D   512
#define NE      320000
#define NE_TOT  (NE + N_NODES)   // + self loops
#define SLOPE   0.2f
#define LN_EPS  1e-5f
#define NPH     5                 // source buckets of 2048 (10000 >> 11 = 4 max)
#define NBUCK   (N_NODES * NPH)
#define NBLK    ((NBUCK + 255) / 256)   // 196 scan blocks

typedef __bf16 bf16x8 __attribute__((ext_vector_type(8)));
typedef float  f32x4  __attribute__((ext_vector_type(4)));
typedef float  f32x2  __attribute__((ext_vector_type(2)));
typedef unsigned short u16;
typedef uint32_t u32;

#if __has_builtin(__builtin_elementwise_fma)
#define PKFMA(a,b,c) __builtin_elementwise_fma((a),(b),(c))
#else
#define PKFMA(a,b,c) ((a)*(b)+(c))
#endif
#if __has_builtin(__builtin_elementwise_max)
#define PKMAX(a,b) __builtin_elementwise_max((a),(b))
#else
static __device__ __forceinline__ f32x2 pkmax_(f32x2 a, f32x2 b) {
    f32x2 r; r.x = fmaxf(a.x, b.x); r.y = fmaxf(a.y, b.y); return r;
}
#define PKMAX(a,b) pkmax_((a),(b))
#endif

__device__ __forceinline__ float bf2f(u16 u) {
    union { u32 i; float f; } v; v.i = ((u32)u) << 16; return v.f;
}
__device__ __forceinline__ u16 f2bf(float f) {
    union { float f; u32 i; } v; v.f = f;
    u32 b = v.i;
    return (u16)((b + 0x7FFFu + ((b >> 16) & 1u)) >> 16);
}
// one dword = 2 packed bf16 -> float2 {lo, hi}
__device__ __forceinline__ f32x2 bfpair(u32 u) {
    union { u32 i; float f; } lo, hi;
    lo.i = u << 16; hi.i = u & 0xFFFF0000u;
    f32x2 r; r.x = lo.f; r.y = hi.f; return r;
}
__device__ __forceinline__ u32 pack2bf(float a, float b) {
    return (u32)f2bf(a) | ((u32)f2bf(b) << 16);
}

// async global->LDS, 16B per lane; LDS dest is wave-uniform base + lane*16 (m104)
__device__ __forceinline__ void gl_lds16(const u16* g, u16* lds_base) {
    __builtin_amdgcn_global_load_lds(
        (const __attribute__((address_space(1))) void*)g,
        (__attribute__((address_space(3))) void*)lds_base, 16, 0, 0);
}

// ---------------- fused prep: dtype-vote + (conditional) canon + bucket-count ----
// canon segments: x(2,560,000) wl1(65,536) wr1(65,536) wl2(131,072) wr2(131,072)
#define CW_X  2560000
#define CW_1  (CW_X + 65536)
#define CW_2  (CW_1 + 65536)
#define CW_3  (CW_2 + 131072)
#define CW_TOT (CW_3 + 131072)            // 2,953,216 = 256 * 11536
#define CANON_BLOCKS (CW_TOT / 256 + 16)  // + 16 blocks for small vectors (4096)
#define COUNT_BLOCKS ((NE + 255) / 256)

struct PrepArgs {
    const void *x, *wl1, *wr1, *wl2, *wr2;
    u16 *xd, *wl1d, *wr1d, *wl2d, *wr2d;
    const void* ssrc[10]; float* sdst[10];
    const int* ei; int* bcnt; int* flagg;
};

__global__ __launch_bounds__(256) void k_prep(PrepArgs c) {
    int bx = blockIdx.x, tid = threadIdx.x;
    if (bx >= CANON_BLOCKS) {           // bucket-count section
        int e = (bx - CANON_BLOCKS) * 256 + tid;
        if (e < NE) {
            int s = c.ei[e], d = c.ei[NE + e];
            atomicAdd(&c.bcnt[d * NPH + (s >> 11)], 1);
        }
        return;
    }
    // local dtype vote (same 256 dwords of x in every block -> deterministic):
    // bf16-packed -> low 16 bits are a bf16 of N(0,1) data, exp field in ~[112,133]
    __shared__ int cnt;
    if (tid == 0) cnt = 0;
    __syncthreads();
    u32 v = ((const u32*)c.x)[tid];
    int e_lo = (int)((v >> 7) & 0xFF);
    if (e_lo >= 100 && e_lo <= 150) atomicAdd(&cnt, 1);
    __syncthreads();
    int f = (cnt > 180) ? 1 : 0;        // 1 = bf16-packed inputs
    if (bx == 0 && tid == 0) *c.flagg = f;

    int i = bx * 256 + tid;
    if (i < CW_TOT) {
        if (f) return;                  // bf16 inputs: GEMM reads d_in directly
        const void* src; u16* dst; int off;
        if      (i < CW_X) { src = c.x;   dst = c.xd;   off = i; }
        else if (i < CW_1) { src = c.wl1; dst = c.wl1d; off = i - CW_X; }
        else if (i < CW_2) { src = c.wr1; dst = c.wr1d; off = i - CW_1; }
        else if (i < CW_3) { src = c.wl2; dst = c.wl2d; off = i - CW_2; }
        else               { src = c.wr2; dst = c.wr2d; off = i - CW_3; }
        dst[off] = f2bf(((const float*)src)[off]);
    } else {
        // small vectors (always run): 4 segs of 256 then 6 segs of 512
        int s = i - CW_TOT;
        int seg, off;
        if (s < 1024) { seg = s >> 8; off = s & 255; }
        else          { seg = 4 + ((s - 1024) >> 9); off = (s - 1024) & 511; }
        const void* sp = c.ssrc[seg];
        float* d = c.sdst[seg];
        d[off] = f ? bf2f(((const u16*)sp)[off]) : ((const float*)sp)[off];
    }
}

// ---------------- parallel 3-phase bucket scan ----------------
// bucket value = bcnt[b] + self-loop (node i's loop goes in bucket (i, i>>11)).
__device__ __forceinline__ int bval_(const int* bcnt, int b) {
    if (b >= NBUCK) return 0;
    int i = b / NPH, ph = b - i * NPH;
    return bcnt[b] + (((i >> 11) == ph) ? 1 : 0);
}

// phase 1: per-block (256-bucket) sums
__global__ __launch_bounds__(256) void k_bsum(const int* __restrict__ bcnt,
                                              int* __restrict__ bsum) {
    __shared__ int sred[256];
    int t = threadIdx.x;
    sred[t] = bval_(bcnt, blockIdx.x * 256 + t);
    __syncthreads();
    #pragma unroll
    for (int o = 128; o > 0; o >>= 1) {
        if (t < o) sred[t] += sred[t + o];
        __syncthreads();
    }
    if (t == 0) bsum[blockIdx.x] = sred[0];
}

// phase 2: exclusive scan of the 196 block sums (in place), single block
__global__ __launch_bounds__(256) void k_bscan(int* __restrict__ bsum,
                                               int* __restrict__ rowptr) {
    __shared__ int sb[2][256];
    int t = threadIdx.x;
    int v = (t < NBLK) ? bsum[t] : 0;
    sb[0][t] = v;
    __syncthreads();
    int cur = 0;
    #pragma unroll
    for (int o = 1; o < 256; o <<= 1) {
        int nxt = cur ^ 1;
        int x = sb[cur][t];
        if (t >= o) x += sb[cur][t - o];
        sb[nxt][t] = x;
        __syncthreads();
        cur = nxt;
    }
    if (t < NBLK) bsum[t] = sb[cur][t] - v;   // exclusive
    if (t == 0) rowptr[N_NODES] = NE_TOT;
}

// phase 3: per-block exclusive scan + block offset -> cursor / rowptr
__global__ __launch_bounds__(256) void k_bapply(const int* __restrict__ bcnt,
                                                const int* __restrict__ bsum,
                                                int* __restrict__ rowptr,
                                                int* __restrict__ cursor) {
    __shared__ int sb[2][256];
    int t = threadIdx.x;
    int b = blockIdx.x * 256 + t;
    int v = bval_(bcnt, b);
    sb[0][t] = v;
    __syncthreads();
    int cur = 0;
    #pragma unroll
    for (int o = 1; o < 256; o <<= 1) {
        int nxt = cur ^ 1;
        int x = sb[cur][t];
        if (t >= o) x += sb[cur][t - o];
        sb[nxt][t] = x;
        __syncthreads();
        cur = nxt;
    }
    if (b < NBUCK) {
        int excl = sb[cur][t] - v + bsum[blockIdx.x];
        cursor[b] = excl;
        int i = b / NPH, ph = b - i * NPH;
        if (ph == 0) rowptr[i] = excl;
    }
}

// ---------------- LDS-tiled GEMM pair (+ bucket-ordered scatter tail blocks) -----
// X/W pointers selected by *flag (raw bf16 inputs vs fp32-canon scratch).
__global__ __launch_bounds__(256) void k_gemm2s(const u16* __restrict__ Xa,   // raw
                                                const u16* __restrict__ Xb,   // canon
                                                const u16* __restrict__ Wla,
                                                const u16* __restrict__ Wlb,
                                                const u16* __restrict__ Wra,
                                                const u16* __restrict__ Wrb,
                                                const float* __restrict__ bl,
                                                const float* __restrict__ br,
                                                u16* __restrict__ Yl,
                                                u16* __restrict__ Yr, int Ncols,
                                                int MBx, int gemmB,
                                                const int* __restrict__ ei,
                                                int* cursor, int* __restrict__ csr_src,
                                                const int* __restrict__ flag) {
    __shared__ uint4 sAq[1024];   // 16 KB: A tile, slot = chunk*128 + m (chunk=k/8)
    __shared__ uint4 sBq[1024];   // 16 KB: B tile, slot = chunk*128 + n
    int bx = blockIdx.x, tid = threadIdx.x;

    if (bx >= gemmB) {            // ordered scatter section
        int e = (bx - gemmB) * 256 + tid;
        if (e < NE_TOT) {
            int s, d;
            if (e < NE) { s = ei[e]; d = ei[NE + e]; }
            else        { s = e - NE; d = s; }
            int pos = atomicAdd(&cursor[d * NPH + (s >> 11)], 1);
            csr_src[pos] = s;
        }
        return;
    }

    int f = *flag;
    const u16* X  = f ? Xa  : Xb;
    const u16* Wl = f ? Wla : Wlb;
    const u16* Wr = f ? Wra : Wrb;

    u16* sA = (u16*)sAq;
    u16* sB = (u16*)sBq;
    int nb = Ncols >> 7;
    int by = bx / MBx;
    const u16* W; const float* bias; u16* Y; int nbase;
    if (by < nb) { W = Wl; bias = bl; Y = Yl; nbase = by << 7; }
    else         { W = Wr; bias = br; Y = Yr; nbase = (by - nb) << 7; }

    int m0   = (bx % MBx) << 7;
    int wave = tid >> 6;
    int lane = tid & 63;
    int quad = lane >> 4;
    int l16  = lane & 15;
    int wm   = wave & 1;
    int wn   = wave >> 1;

    f32x4 acc[4][4] = {};

    #pragma unroll 1
    for (int kk = 0; kk < K_DIM; kk += 64) {
        #pragma unroll
        for (int r = 0; r < 4; ++r) {
            int g = wave + r * 4;
            int chunk = g >> 1;
            int row = ((g & 1) << 6) + lane;
            int mg = m0 + row;
            if (mg >= N_NODES) mg = N_NODES - 1;   // clamp: dup data, stores guarded
            gl_lds16(X + (size_t)mg * K_DIM + kk + chunk * 8, sA + (size_t)(g << 6) * 8);
            gl_lds16(W + (size_t)(nbase + row) * K_DIM + kk + chunk * 8, sB + (size_t)(g << 6) * 8);
        }
        __syncthreads();

        #pragma unroll
        for (int s = 0; s < 2; ++s) {
            int c = s * 4 + quad;
            bf16x8 af[4], bf[4];
            #pragma unroll
            for (int t = 0; t < 4; ++t) {
                int m = (wm << 6) + t * 16 + l16;
                af[t] = *(const bf16x8*)(sA + ((size_t)(c << 7) + m) * 8);
                int n = (wn << 6) + t * 16 + l16;
                bf[t] = *(const bf16x8*)(sB + ((size_t)(c << 7) + n) * 8);
            }
            #pragma unroll
            for (int mt = 0; mt < 4; ++mt)
                #pragma unroll
                for (int nt = 0; nt < 4; ++nt)
                    acc[mt][nt] = __builtin_amdgcn_mfma_f32_16x16x32_bf16(
                        af[mt], bf[nt], acc[mt][nt], 0, 0, 0);
        }
        __syncthreads();
    }

    #pragma unroll
    for (int nt = 0; nt < 4; ++nt) {
        int col = nbase + (wn << 6) + nt * 16 + l16;
        float bv = bias[col];
        #pragma unroll
        for (int mt = 0; mt < 4; ++mt) {
            int rbase = m0 + (wm << 6) + mt * 16 + quad * 4;
            #pragma unroll
            for (int q = 0; q < 4; ++q) {
                int row = rbase + q;
                if (row < N_NODES)
                    Y[(size_t)row * Ncols + col] = f2bf(acc[mt][nt][q] + bv);
            }
        }
    }
}

// ---------------- Layer-1 fused attention + aggregation (+bias+ReLU) ----------------
// 1 wave/node (4 nodes/block); lane owns 4 ch: c0 = head*64+(lane&15)*4.
__global__ __launch_bounds__(256) void k_agg1(const u16* __restrict__ xl,
                                              const u16* __restrict__ xr,
                                              const int* __restrict__ rowptr,
                                              const int* __restrict__ csrc,
                                              const float* __restrict__ att,
                                              const float* __restrict__ bias,
                                              u16* __restrict__ hout) {
    int wave = threadIdx.x >> 6, lane = threadIdx.x & 63;
    int i = blockIdx.x * 4 + wave;
    if (i >= N_NODES) return;
    int c0 = (lane >> 4) * 64 + (lane & 15) * 4;

    f32x2 xp[2], ap[2];
    {
        uint2 xq = *(const uint2*)(xr + (size_t)i * HID_D + c0);
        xp[0] = bfpair(xq.x); xp[1] = bfpair(xq.y);
        const f32x2* a2 = (const f32x2*)(att + c0);
        ap[0] = a2[0]; ap[1] = a2[1];
    }
    const f32x2 slope2 = {SLOPE, SLOPE};

    int p = rowptr[i], pend = rowptr[i + 1];
    float denom = 0.f;
    f32x2 acc[2] = {};
    const u16* xbase = xl + c0;

    auto dotq = [&](uint2 q) -> float {
        f32x2 pr2 = {0.f, 0.f};
        f32x2 s = bfpair(q.x) + xp[0]; s = PKMAX(s, s * slope2); pr2 = PKFMA(s, ap[0], pr2);
        s = bfpair(q.y) + xp[1];       s = PKMAX(s, s * slope2); pr2 = PKFMA(s, ap[1], pr2);
        return pr2.x + pr2.y;
    };
    auto accq = [&](uint2 q, float w) {
        f32x2 W = {w, w};
        acc[0] = PKFMA(W, bfpair(q.x), acc[0]);
        acc[1] = PKFMA(W, bfpair(q.y), acc[1]);
    };

    while (p + 8 <= pend) {
        int4 ja = *(const int4*)(csrc + p);
        int4 jb = *(const int4*)(csrc + p + 4);
        uint2 q[8];
        q[0] = *(const uint2*)(xbase + (size_t)ja.x * HID_D);
        q[1] = *(const uint2*)(xbase + (size_t)ja.y * HID_D);
        q[2] = *(const uint2*)(xbase + (size_t)ja.z * HID_D);
        q[3] = *(const uint2*)(xbase + (size_t)ja.w * HID_D);
        q[4] = *(const uint2*)(xbase + (size_t)jb.x * HID_D);
        q[5] = *(const uint2*)(xbase + (size_t)jb.y * HID_D);
        q[6] = *(const uint2*)(xbase + (size_t)jb.z * HID_D);
        q[7] = *(const uint2*)(xbase + (size_t)jb.w * HID_D);
        float pr[8];
        #pragma unroll
        for (int e = 0; e < 8; ++e) pr[e] = dotq(q[e]);
        #pragma unroll
        for (int o = 1; o < 16; o <<= 1)
            #pragma unroll
            for (int e = 0; e < 8; ++e) pr[e] += __shfl_xor(pr[e], o, 64);
        #pragma unroll
        for (int e = 0; e < 8; ++e) {
            float w = __expf(fminf(pr[e], 60.f));
            denom += w;
            accq(q[e], w);
        }
        p += 8;
    }
    if (p + 4 <= pend) {
        int4 ja = *(const int4*)(csrc + p);
        uint2 q[4];
        q[0] = *(const uint2*)(xbase + (size_t)ja.x * HID_D);
        q[1] = *(const uint2*)(xbase + (size_t)ja.y * HID_D);
        q[2] = *(const uint2*)(xbase + (size_t)ja.z * HID_D);
        q[3] = *(const uint2*)(xbase + (size_t)ja.w * HID_D);
        float pr[4];
        #pragma unroll
        for (int e = 0; e < 4; ++e) pr[e] = dotq(q[e]);
        #pragma unroll
        for (int o = 1; o < 16; o <<= 1)
            #pragma unroll
            for (int e = 0; e < 4; ++e) pr[e] += __shfl_xor(pr[e], o, 64);
        #pragma unroll
        for (int e = 0; e < 4; ++e) {
            float w = __expf(fminf(pr[e], 60.f));
            denom += w;
            accq(q[e], w);
        }
        p += 4;
    }
    for (; p < pend; ++p) {
        uint2 q = *(const uint2*)(xbase + (size_t)csrc[p] * HID_D);
        float pr = dotq(q);
        #pragma unroll
        for (int o = 1; o < 16; o <<= 1) pr += __shfl_xor(pr, o, 64);
        float w = __expf(fminf(pr, 60.f));
        denom += w;
        accq(q, w);
    }

    float inv = 1.f / denom;
    f32x2 inv2 = {inv, inv};
    const f32x2* bp = (const f32x2*)(bias + c0);
    f32x2 z = {0.f, 0.f};
    f32x2 o0 = PKMAX(PKFMA(acc[0], inv2, bp[0]), z);   // + bias, ReLU
    f32x2 o1 = PKMAX(PKFMA(acc[1], inv2, bp[1]), z);
    u32* hp = (u32*)(hout + (size_t)i * HID_D + c0);
    hp[0] = pack2bf(o0.x, o0.y);
    hp[1] = pack2bf(o1.x, o1.y);
}

// ---------------- Layer-2 fused attention + aggregation + LayerNorm ----------------
// 1 wave/node; lane owns 8 ch: c0 = head*128+(lane&15)*8. Bucket-sorted lists.
__global__ __launch_bounds__(256) void k_agg2_ln(const u16* __restrict__ xl,
                                                 const u16* __restrict__ xr,
                                                 const int* __restrict__ rowptr,
                                                 const int* __restrict__ csrc,
                                                 const float* __restrict__ att,
                                                 const float* __restrict__ bias,
                                                 const float* __restrict__ gamma,
                                                 const float* __restrict__ beta,
                                                 void* __restrict__ outv,
                                                 const int* __restrict__ flag) {
    int wave = threadIdx.x >> 6, lane = threadIdx.x & 63;
    int i = blockIdx.x * 4 + wave;
    if (i >= N_NODES) return;
    int c0 = (lane >> 4) * 128 + (lane & 15) * 8;

    f32x2 xp[4], ap[4];
    {
        uint4 xq = *(const uint4*)(xr + (size_t)i * OUT_D + c0);
        xp[0] = bfpair(xq.x); xp[1] = bfpair(xq.y);
        xp[2] = bfpair(xq.z); xp[3] = bfpair(xq.w);
        const f32x2* a2 = (const f32x2*)(att + c0);
        ap[0] = a2[0]; ap[1] = a2[1]; ap[2] = a2[2]; ap[3] = a2[3];
    }
    const f32x2 slope2 = {SLOPE, SLOPE};

    int p = rowptr[i], pend = rowptr[i + 1];
    float denom = 0.f;
    f32x2 acc[4] = {};
    const u16* xbase = xl + c0;

    auto dotq = [&](uint4 q) -> float {
        f32x2 pr2 = {0.f, 0.f};
        f32x2 s = bfpair(q.x) + xp[0]; s = PKMAX(s, s * slope2); pr2 = PKFMA(s, ap[0], pr2);
        s = bfpair(q.y) + xp[1];       s = PKMAX(s, s * slope2); pr2 = PKFMA(s, ap[1], pr2);
        s = bfpair(q.z) + xp[2];       s = PKMAX(s, s * slope2); pr2 = PKFMA(s, ap[2], pr2);
        s = bfpair(q.w) + xp[3];       s = PKMAX(s, s * slope2); pr2 = PKFMA(s, ap[3], pr2);
        return pr2.x + pr2.y;
    };
    auto accq = [&](uint4 q, float w) {
        f32x2 W = {w, w};
        acc[0] = PKFMA(W, bfpair(q.x), acc[0]);
        acc[1] = PKFMA(W, bfpair(q.y), acc[1]);
        acc[2] = PKFMA(W, bfpair(q.z), acc[2]);
        acc[3] = PKFMA(W, bfpair(q.w), acc[3]);
    };

    while (p + 8 <= pend) {
        int4 ja = *(const int4*)(csrc + p);
        int4 jb = *(const int4*)(csrc + p + 4);
        uint4 q[8];
        q[0] = *(const uint4*)(xbase + (size_t)ja.x * OUT_D);
        q[1] = *(const uint4*)(xbase + (size_t)ja.y * OUT_D);
        q[2] = *(const uint4*)(xbase + (size_t)ja.z * OUT_D);
        q[3] = *(const uint4*)(xbase + (size_t)ja.w * OUT_D);
        q[4] = *(const uint4*)(xbase + (size_t)jb.x * OUT_D);
        q[5] = *(const uint4*)(xbase + (size_t)jb.y * OUT_D);
        q[6] = *(const uint4*)(xbase + (size_t)jb.z * OUT_D);
        q[7] = *(const uint4*)(xbase + (size_t)jb.w * OUT_D);
        float pr[8];
        #pragma unroll
        for (int e = 0; e < 8; ++e) pr[e] = dotq(q[e]);
        #pragma unroll
        for (int o = 1; o < 16; o <<= 1)
            #pragma unroll
            for (int e = 0; e < 8; ++e) pr[e] += __shfl_xor(pr[e], o, 64);
        #pragma unroll
        for (int e = 0; e < 8; ++e) {
            float w = __expf(fminf(pr[e], 60.f));
            denom += w;
            accq(q[e], w);
        }
        p += 8;
    }
    if (p + 4 <= pend) {
        int4 ja = *(const int4*)(csrc + p);
        uint4 q[4];
        q[0] = *(const uint4*)(xbase + (size_t)ja.x * OUT_D);
        q[1] = *(const uint4*)(xbase + (size_t)ja.y * OUT_D);
        q[2] = *(const uint4*)(xbase + (size_t)ja.z * OUT_D);
        q[3] = *(const uint4*)(xbase + (size_t)ja.w * OUT_D);
        float pr[4];
        #pragma unroll
        for (int e = 0; e < 4; ++e) pr[e] = dotq(q[e]);
        #pragma unroll
        for (int o = 1; o < 16; o <<= 1)
            #pragma unroll
            for (int e = 0; e < 4; ++e) pr[e] += __shfl_xor(pr[e], o, 64);
        #pragma unroll
        for (int e = 0; e < 4; ++e) {
            float w = __expf(fminf(pr[e], 60.f));
            denom += w;
            accq(q[e], w);
        }
        p += 4;
    }
    for (; p < pend; ++p) {
        uint4 q = *(const uint4*)(xbase + (size_t)csrc[p] * OUT_D);
        float pr = dotq(q);
        #pragma unroll
        for (int o = 1; o < 16; o <<= 1) pr += __shfl_xor(pr, o, 64);
        float w = __expf(fminf(pr, 60.f));
        denom += w;
        accq(q, w);
    }

    float inv = 1.f / denom;
    f32x2 inv2 = {inv, inv};
    const f32x2* bp = (const f32x2*)(bias + c0);
    f32x2 o2[4];
    float s1 = 0.f, s2 = 0.f;
    #pragma unroll
    for (int k = 0; k < 4; ++k) {
        o2[k] = PKFMA(acc[k], inv2, bp[k]);
        s1 += o2[k].x + o2[k].y;
        s2 = fmaf(o2[k].x, o2[k].x, fmaf(o2[k].y, o2[k].y, s2));
    }
    #pragma unroll
    for (int off = 1; off < 64; off <<= 1) {
        s1 += __shfl_xor(s1, off, 64);
        s2 += __shfl_xor(s2, off, 64);
    }
    float mu  = s1 * (1.f / OUT_D);
    float var = s2 * (1.f / OUT_D) - mu * mu;
    float rstd = rsqrtf(var + LN_EPS);
    f32x2 mu2 = {mu, mu}, rs2 = {rstd, rstd};
    const f32x2* gp  = (const f32x2*)(gamma + c0);
    const f32x2* bep = (const f32x2*)(beta + c0);

    size_t ob = (size_t)i * OUT_D + c0;
    if (*flag) {
        u32 pk[4];
        #pragma unroll
        for (int k = 0; k < 4; ++k) {
            f32x2 r = PKFMA(gp[k] * (o2[k] - mu2), rs2, bep[k]);
            pk[k] = pack2bf(r.x, r.y);
        }
        *(uint4*)((u16*)outv + ob) = make_uint4(pk[0], pk[1], pk[2], pk[3]);
    } else {
        f32x2* out = (f32x2*)((float*)outv + ob);
        #pragma unroll
        for (int k = 0; k < 4; ++k)
            out[k] = PKFMA(gp[k] * (o2[k] - mu2), rs2, bep[k]);
    }
}

// ---------------- launcher ----------------

extern "C" void kernel_launch(void* const* d_in, const int* in_sizes, int n_in,
                              void* d_out, int out_size, void* d_ws, size_t ws_size,
                              hipStream_t stream) {
    const int* ei = (const int*)d_in[1];

    char* ws = (char*)d_ws;
    size_t off = 0;
    auto alloc = [&](size_t bytes) { void* p = ws + off; off += (bytes + 255) & ~(size_t)255; return p; };
    u16* xcb  = (u16*)alloc((size_t)N_NODES * K_DIM * 2);
    u16* wl1b = (u16*)alloc((size_t)HID_D * K_DIM * 2);
    u16* wr1b = (u16*)alloc((size_t)HID_D * K_DIM * 2);
    u16* wl2b = (u16*)alloc((size_t)OUT_D * K_DIM * 2);
    u16* wr2b = (u16*)alloc((size_t)OUT_D * K_DIM * 2);
    u16* xl1b = (u16*)alloc((size_t)N_NODES * HID_D * 2);
    u16* xr1b = (u16*)alloc((size_t)N_NODES * HID_D * 2);
    u16* hb   = (u16*)alloc((size_t)N_NODES * HID_D * 2);
    u16* xl2b = (u16*)alloc((size_t)N_NODES * OUT_D * 2);
    u16* xr2b = (u16*)alloc((size_t)N_NODES * OUT_D * 2);
    float* bl1c  = (float*)alloc(HID_D * 4);
    float* br1c  = (float*)alloc(HID_D * 4);
    float* att1c = (float*)alloc(HID_D * 4);
    float* bia1c = (float*)alloc(HID_D * 4);
    float* bl2c  = (float*)alloc(OUT_D * 4);
    float* br2c  = (float*)alloc(OUT_D * 4);
    float* att2c = (float*)alloc(OUT_D * 4);
    float* bia2c = (float*)alloc(OUT_D * 4);
    float* gamc  = (float*)alloc(OUT_D * 4);
    float* betc  = (float*)alloc(OUT_D * 4);
    int* flag = (int*)alloc(256);
    int* bcnt = (int*)alloc((size_t)NBUCK * 4);
    int* bsum = (int*)alloc((size_t)NBLK * 4);
    int* rowp = (int*)alloc((size_t)(N_NODES + 1) * 4);
    int* curs = (int*)alloc((size_t)NBUCK * 4);
    int* csrc = (int*)alloc((size_t)NE_TOT * 4);

    hipMemsetAsync(bcnt, 0, (size_t)NBUCK * 4, stream);

    PrepArgs pa;
    pa.x = d_in[0]; pa.wl1 = d_in[2]; pa.wr1 = d_in[4]; pa.wl2 = d_in[8]; pa.wr2 = d_in[10];
    pa.xd = xcb; pa.wl1d = wl1b; pa.wr1d = wr1b; pa.wl2d = wl2b; pa.wr2d = wr2b;
    pa.ssrc[0] = d_in[3];  pa.sdst[0] = bl1c;
    pa.ssrc[1] = d_in[5];  pa.sdst[1] = br1c;
    pa.ssrc[2] = d_in[6];  pa.sdst[2] = att1c;
    pa.ssrc[3] = d_in[7];  pa.sdst[3] = bia1c;
    pa.ssrc[4] = d_in[9];  pa.sdst[4] = bl2c;
    pa.ssrc[5] = d_in[11]; pa.sdst[5] = br2c;
    pa.ssrc[6] = d_in[12]; pa.sdst[6] = att2c;
    pa.ssrc[7] = d_in[13]; pa.sdst[7] = bia2c;
    pa.ssrc[8] = d_in[14]; pa.sdst[8] = gamc;
    pa.ssrc[9] = d_in[15]; pa.sdst[9] = betc;
    pa.ei = ei; pa.bcnt = bcnt; pa.flagg = flag;
    hipLaunchKernelGGL(k_prep, dim3(CANON_BLOCKS + COUNT_BLOCKS), dim3(256), 0, stream, pa);

    // parallel 3-phase bucket scan
    hipLaunchKernelGGL(k_bsum,   dim3(NBLK), dim3(256), 0, stream, bcnt, bsum);
    hipLaunchKernelGGL(k_bscan,  dim3(1),    dim3(256), 0, stream, bsum, rowp);
    hipLaunchKernelGGL(k_bapply, dim3(NBLK), dim3(256), 0, stream, bcnt, bsum, rowp, curs);

    const int MB = (N_NODES + 127) / 128;     // 79
    const int SCATB = (NE_TOT + 255) / 256;   // 1290
    // layer-1 GEMM pair + ordered-scatter tail blocks
    hipLaunchKernelGGL(k_gemm2s, dim3(MB * 4 + SCATB), dim3(256), 0, stream,
                       (const u16*)d_in[0], xcb,
                       (const u16*)d_in[2], wl1b,
                       (const u16*)d_in[4], wr1b,
                       bl1c, br1c, xl1b, xr1b, HID_D,
                       MB, MB * 4, ei, curs, csrc, flag);
    hipLaunchKernelGGL(k_agg1, dim3((N_NODES + 3) / 4), dim3(256), 0, stream,
                       xl1b, xr1b, rowp, csrc, att1c, bia1c, hb);
    // layer-2 GEMM pair (X = hb from scratch; raw==canon)
    hipLaunchKernelGGL(k_gemm2s, dim3(MB * 8), dim3(256), 0, stream,
                       hb, hb,
                       (const u16*)d_in[8], wl2b,
                       (const u16*)d_in[10], wr2b,
                       bl2c, br2c, xl2b, xr2b, OUT_D,
                       MB, MB * 8, ei, curs, csrc, flag);
    hipLaunchKernelGGL(k_agg2_ln, dim3((N_NODES + 3) / 4), dim3(256), 0, stream,
                       xl2b, xr2b, rowp, csrc, att2c, bia2c, gamc, betc, d_out, flag);
}